// Round 6
// baseline (907.794 us; speedup 1.0000x reference)
//
#include <hip/hip_runtime.h>

#define TT 256
#define BATCH 2048
#define DATA 32
#define WSLOTS 52

typedef __bf16 bf16x8 __attribute__((ext_vector_type(8)));
typedef float f32x4 __attribute__((ext_vector_type(4)));

union bfp2 { uint2 u; __bf16 b[4]; };

// fp32 x8 (global) -> bf16x8 fragment (prologue only)
__device__ __forceinline__ bf16x8 ldw8(const float* __restrict__ p) {
    float4 a = *(const float4*)p;
    float4 b = *(const float4*)(p + 4);
    bf16x8 r;
    r[0] = (__bf16)a.x; r[1] = (__bf16)a.y; r[2] = (__bf16)a.z; r[3] = (__bf16)a.w;
    r[4] = (__bf16)b.x; r[5] = (__bf16)b.y; r[6] = (__bf16)b.z; r[7] = (__bf16)b.w;
    return r;
}

// swizzled LDS fragment read: 256-B row stride, 16-B slot XOR (row&7)
__device__ __forceinline__ bf16x8 ldx(const char* base, int row, int kbyte) {
    return *(const bf16x8*)(base + row * 256 + (kbyte ^ ((row & 7) << 4)));
}

// raw workgroup barrier: LDS-complete only, never drains vmcnt (out-stores fly free)
__device__ __forceinline__ void wg_barrier() {
    asm volatile("s_waitcnt lgkmcnt(0)" ::: "memory");
    __builtin_amdgcn_sched_barrier(0);
    __builtin_amdgcn_s_barrier();
    __builtin_amdgcn_sched_barrier(0);
}

// Hidden layer, this wave's 2 of 8 N-tiles. A=weight frags (regs), B=xf.
// D: lane&15 = batch row m, cols (lane>>4)*4+j -> one b64 store per tile.
#define HIDL(WF, KC, XEXPR, DST, B0, B1)                                              \
    {                                                                                 \
        bf16x8 xf[4];                                                                 \
        _Pragma("unroll") for (int kc = 0; kc < (KC); ++kc) xf[kc] = XEXPR(kc);       \
        f32x4 a0 = B0, a1 = B1;                                                       \
        _Pragma("unroll") for (int kc = 0; kc < (KC); ++kc) {                         \
            a0 = __builtin_amdgcn_mfma_f32_16x16x32_bf16(WF[0][kc], xf[kc], a0, 0, 0, 0); \
            a1 = __builtin_amdgcn_mfma_f32_16x16x32_bf16(WF[1][kc], xf[kc], a1, 0, 0, 0); \
        }                                                                             \
        bfp2 p0, p1;                                                                  \
        _Pragma("unroll") for (int j = 0; j < 4; ++j) {                               \
            p0.b[j] = (__bf16)fmaxf(a0[j], 0.0f);                                     \
            p1.b[j] = (__bf16)fmaxf(a1[j], 0.0f);                                     \
        }                                                                             \
        char* dr = (DST) + m * 256;                                                   \
        *(uint2*)(dr + ((tbB + g * 8) ^ sw)) = p0.u;                                  \
        *(uint2*)(dr + ((tbB + 32 + g * 8) ^ sw)) = p1.u;                             \
    }

#define XW_FRAG(kc) (*(const bf16x8*)(xrow + (kc) * 64 + xoff))
#define HA_FRAG(kc) ldx(hA, m, (kc) * 64 + g * 16)
#define HB_FRAG(kc) ldx(hB, m, (kc) * 64 + g * 16)
#define HC_FRAG(kc) ldx(hC, m, (kc) * 64 + g * 16)

// Assemble x = [y_stage | lerp(hist,tq-1) | lerp(hist,tq-2)] in this wave's xw
// scratch (per-lane-owned cells, same-wave consumers -> no barrier).
#define ASSEMBLE(USEK, CST, KP)                                                       \
    {                                                                                 \
        _Pragma("unroll") for (int t2 = 0; t2 < 2; ++t2) {                            \
            bfp2 p;                                                                   \
            _Pragma("unroll") for (int j = 0; j < 4; ++j) {                           \
                const float v = (USEK) ? fmaf((CST) * dt, KP[t2][j], y[t2][j])        \
                                       : y[t2][j];                                    \
                p.b[j] = (__bf16)v;                                                   \
            }                                                                         \
            *(uint2*)(xrow + t2 * 32 + g * 8) = p.u;                                  \
        }                                                                             \
        const float tq = fmaf((CST), dt, t);                                          \
        _Pragma("unroll") for (int dl = 0; dl < 2; ++dl) {                            \
            float s = (tq - (dl ? 2.0f : 1.0f) - t0v) * ivd0;                         \
            s = fminf(fmaxf(s, 0.0f), 255.0f);                                        \
            const int   i0 = (int)s;                                                  \
            const int   i1 = min(i0 + 1, TT - 1);                                     \
            const float w  = s - (float)i0;                                           \
            const char* h0p = histc + (i0 % WSLOTS) * 1152 + m * 72;                  \
            const char* h1p = histc + (i1 % WSLOTS) * 1152 + m * 72;                  \
            _Pragma("unroll") for (int t2 = 0; t2 < 2; ++t2) {                        \
                bfp2 pa, pb, pr;                                                      \
                pa.u = *(const uint2*)(h0p + t2 * 32 + g * 8);                        \
                pb.u = *(const uint2*)(h1p + t2 * 32 + g * 8);                        \
                _Pragma("unroll") for (int j = 0; j < 4; ++j) {                       \
                    const float va = (float)pa.b[j];                                  \
                    pr.b[j] = (__bf16)fmaf(w, (float)pb.b[j] - va, va);               \
                }                                                                     \
                *(uint2*)(xrow + (1 + dl) * 64 + t2 * 32 + g * 8) = pr.u;             \
            }                                                                         \
        }                                                                             \
        asm volatile("s_waitcnt lgkmcnt(0)" ::: "memory");                            \
        __builtin_amdgcn_sched_barrier(0);                                            \
    }

#define DO_STAGE(USEK, CST, KP, KD)                                                   \
    ASSEMBLE(USEK, CST, KP)                                                           \
    HIDL(W0f, 3, XW_FRAG, hA, bias0[0], bias0[1])                                     \
    wg_barrier();                                                                     \
    HIDL(W1f, 4, HA_FRAG, hB, bias1[0], bias1[1])                                     \
    wg_barrier();                                                                     \
    HIDL(W2f, 4, HB_FRAG, hC, bias2[0], bias2[1])                                     \
    wg_barrier();                                                                     \
    {   /* L3: all waves redundantly -> full k in-register everywhere */              \
        bf16x8 xf[4];                                                                 \
        _Pragma("unroll") for (int kc = 0; kc < 4; ++kc) xf[kc] = HC_FRAG(kc);        \
        _Pragma("unroll") for (int t2 = 0; t2 < 2; ++t2) {                            \
            f32x4 a = bias3[t2];                                                      \
            _Pragma("unroll") for (int kc = 0; kc < 4; ++kc)                          \
                a = __builtin_amdgcn_mfma_f32_16x16x32_bf16(W3f[t2][kc], xf[kc], a, 0, 0, 0); \
            KD[t2] = a;                                                               \
        }                                                                             \
    }

__global__ __launch_bounds__(256, 1) void dde_3b(
    const float* __restrict__ ts, const float* __restrict__ y0,
    const float* __restrict__ W0, const float* __restrict__ b0,
    const float* __restrict__ W1, const float* __restrict__ b1,
    const float* __restrict__ W2, const float* __restrict__ b2,
    const float* __restrict__ W3, const float* __restrict__ b3,
    float* __restrict__ out)
{
    __shared__ __align__(16) unsigned short hist[WSLOTS][16][36]; // 59904 B
    __shared__ __align__(16) char hA[16 * 256];
    __shared__ __align__(16) char hB[16 * 256];
    __shared__ __align__(16) char hC[16 * 256];
    __shared__ __align__(16) char xw[4][16 * 208];                // per-wave x scratch
    __shared__ float tsb[TT];
    // ~87 KB LDS

    const int tid  = threadIdx.x;
    const int lane = tid & 63;
    const int wv   = tid >> 6;        // wave 0..3 -> N-tile pair for hidden layers
    const int m    = lane & 15;       // batch row within block
    const int g    = lane >> 4;       // k-group / col-quad
    const int tbB  = wv * 64;         // byte base of this wave's first hidden tile
    const int sw   = (m & 7) << 4;
    const int xoff = (g >> 1) * 32 + (g & 1) * 16;
    const int R0   = blockIdx.x * 16;
    char* histc = (char*)hist;
    char* xrow  = xw[wv] + m * 208;

    for (int idx = tid; idx < WSLOTS * 16 * 18; idx += 256) ((unsigned*)hist)[idx] = 0u;
    for (int idx = tid; idx < TT; idx += 256) tsb[idx] = ts[idx];

    // ---- register-resident weight fragments (all waves: W3 both tiles) ----
    bf16x8 W0f[2][3], W1f[2][4], W2f[2][4], W3f[2][4];
    #pragma unroll
    for (int ti = 0; ti < 2; ++ti) {
        const int rw = (wv * 2 + ti) * 16 + m;
        #pragma unroll
        for (int kc = 0; kc < 3; ++kc) W0f[ti][kc] = ldw8(W0 + rw * 96 + kc * 32 + g * 8);
        #pragma unroll
        for (int kc = 0; kc < 4; ++kc) W1f[ti][kc] = ldw8(W1 + rw * 128 + kc * 32 + g * 8);
        #pragma unroll
        for (int kc = 0; kc < 4; ++kc) W2f[ti][kc] = ldw8(W2 + rw * 128 + kc * 32 + g * 8);
        #pragma unroll
        for (int kc = 0; kc < 4; ++kc) W3f[ti][kc] = ldw8(W3 + (ti * 16 + m) * 128 + kc * 32 + g * 8);
    }
    f32x4 bias0[2], bias1[2], bias2[2], bias3[2];
    #pragma unroll
    for (int ti = 0; ti < 2; ++ti) {
        bias0[ti] = *(const f32x4*)(b0 + (wv * 2 + ti) * 16 + g * 4);
        bias1[ti] = *(const f32x4*)(b1 + (wv * 2 + ti) * 16 + g * 4);
        bias2[ti] = *(const f32x4*)(b2 + (wv * 2 + ti) * 16 + g * 4);
        bias3[ti] = *(const f32x4*)(b3 + ti * 16 + g * 4);
    }

    __syncthreads();   // hist zero complete

    // ---- init y (replicated in every wave), hist slot 0, out[0] ----
    f32x4 y[2], k1[2], k2[2], k3[2];
    #pragma unroll
    for (int t2 = 0; t2 < 2; ++t2) {
        float4 v = *(const float4*)(y0 + (R0 + m) * DATA + t2 * 16 + g * 4);
        y[t2][0] = v.x; y[t2][1] = v.y; y[t2][2] = v.z; y[t2][3] = v.w;
        k1[t2] = y[t2]; k2[t2] = y[t2]; k3[t2] = y[t2];
        if (wv == 0) {
            bfp2 p;
            p.b[0] = (__bf16)v.x; p.b[1] = (__bf16)v.y;
            p.b[2] = (__bf16)v.z; p.b[3] = (__bf16)v.w;
            *(uint2*)(histc + m * 72 + t2 * 32 + g * 8) = p.u;
            *(float4*)(out + (R0 + m) * DATA + t2 * 16 + g * 4) = v;
        }
    }
    if (blockIdx.x == 0 && tid == 0)
        out[(size_t)TT * BATCH * DATA] = 255.0f;   // tuple output 1: int32(T-1)
    __syncthreads();

    const float t0v  = tsb[0];
    const float ivd0 = 1.0f / (tsb[1] - tsb[0]);

    #pragma unroll 1
    for (int i = 0; i < TT - 1; ++i) {
        const float t  = tsb[i];
        const float dt = tsb[i + 1] - t;

        DO_STAGE(0, 0.0f,  k1, k1)
        DO_STAGE(1, 0.5f,  k1, k2)
        DO_STAGE(2, 0.75f, k2, k3)

        {
            const int ws = (i + 1) % WSLOTS;
            #pragma unroll
            for (int t2 = 0; t2 < 2; ++t2) {
                #pragma unroll
                for (int j = 0; j < 4; ++j) {
                    const float ks = (2.0f / 9.0f) * k1[t2][j] + (1.0f / 3.0f) * k2[t2][j]
                                   + (4.0f / 9.0f) * k3[t2][j];
                    y[t2][j] = fmaf(dt, ks, y[t2][j]);
                }
                if (wv == 0) {
                    bfp2 p; float4 v;
                    p.b[0] = (__bf16)y[t2][0]; p.b[1] = (__bf16)y[t2][1];
                    p.b[2] = (__bf16)y[t2][2]; p.b[3] = (__bf16)y[t2][3];
                    v.x = y[t2][0]; v.y = y[t2][1]; v.z = y[t2][2]; v.w = y[t2][3];
                    *(uint2*)(histc + ws * 1152 + m * 72 + t2 * 32 + g * 8) = p.u;
                    *(float4*)(out + (size_t)(i + 1) * BATCH * DATA
                               + (R0 + m) * DATA + t2 * 16 + g * 4) = v;
                }
            }
        }
        // hist slot (i+1) is not read for >=25 further steps (>=75 barriers) ->
        // cross-wave visibility guaranteed; h buffers rotate A->B->C with >=2
        // barriers between last read and next write.
    }
}

extern "C" void kernel_launch(void* const* d_in, const int* in_sizes, int n_in,
                              void* d_out, int out_size, void* d_ws, size_t ws_size,
                              hipStream_t stream) {
    const float* ts = (const float*)d_in[0];
    const float* y0 = (const float*)d_in[1];
    const float* W0 = (const float*)d_in[2];
    const float* b0 = (const float*)d_in[3];
    const float* W1 = (const float*)d_in[4];
    const float* b1 = (const float*)d_in[5];
    const float* W2 = (const float*)d_in[6];
    const float* b2 = (const float*)d_in[7];
    const float* W3 = (const float*)d_in[8];
    const float* b3 = (const float*)d_in[9];

    dde_3b<<<dim3(BATCH / 16), dim3(256), 0, stream>>>(
        ts, y0, W0, b0, W1, b1, W2, b2, W3, b3, (float*)d_out);
}

// Round 7
// 868.447 us; speedup vs baseline: 1.0453x; 1.0453x over previous
//
#include <hip/hip_runtime.h>

#define TT 256
#define BATCH 2048
#define DATA 32
#define WSLOTS 52

typedef __bf16 bf16x8 __attribute__((ext_vector_type(8)));
typedef float f32x4 __attribute__((ext_vector_type(4)));

#define MFMA(A, B, C) __builtin_amdgcn_mfma_f32_16x16x32_bf16((A), (B), (C), 0, 0, 0)

union bp4 { uint2 u; __bf16 b[4]; };

// fp32 x8 (global) -> bf16x8 fragment (prologue only)
__device__ __forceinline__ bf16x8 ldw8(const float* __restrict__ p) {
    float4 a = *(const float4*)p;
    float4 b = *(const float4*)(p + 4);
    bf16x8 r;
    r[0] = (__bf16)a.x; r[1] = (__bf16)a.y; r[2] = (__bf16)a.z; r[3] = (__bf16)a.w;
    r[4] = (__bf16)b.x; r[5] = (__bf16)b.y; r[6] = (__bf16)b.z; r[7] = (__bf16)b.w;
    return r;
}

// raw workgroup barrier: LDS-complete only, never drains vmcnt (out-stores fly free)
__device__ __forceinline__ void wg_barrier() {
    asm volatile("s_waitcnt lgkmcnt(0)" ::: "memory");
    __builtin_amdgcn_sched_barrier(0);
    __builtin_amdgcn_s_barrier();
    __builtin_amdgcn_sched_barrier(0);
}

// One RK stage, all waves symmetric, 3 barriers.
// State (y, k*) is fp32 in B-layout: lane (m,g) owns features g*8..g*8+7 of sample m.
#define DO_STAGE(USEK, CST, KP, KD)                                                   \
    {                                                                                 \
        /* ---- assemble x = [yst | lerp(tq-1) | lerp(tq-2)] fully in-register ---- */\
        bf16x8 xf0, xf1, xf2;                                                         \
        {                                                                             \
            const float tq = fmaf((CST), dt, t);                                      \
            float s1 = (tq - 1.0f - t0v) * ivd0;                                      \
            float s2 = (tq - 2.0f - t0v) * ivd0;                                      \
            s1 = fminf(fmaxf(s1, 0.0f), 255.0f);                                      \
            s2 = fminf(fmaxf(s2, 0.0f), 255.0f);                                      \
            const int   a0i = (int)s1, b0i = (int)s2;                                 \
            const int   a1i = min(a0i + 1, TT - 1), b1i = min(b0i + 1, TT - 1);       \
            const float wa = s1 - (float)a0i, wb = s2 - (float)b0i;                   \
            const char* hp = hists + g * 256 + m * 16;                                \
            bf16x8 ha0 = *(const bf16x8*)(hp + (a0i % WSLOTS) * 1024);                \
            bf16x8 ha1 = *(const bf16x8*)(hp + (a1i % WSLOTS) * 1024);                \
            bf16x8 hb0 = *(const bf16x8*)(hp + (b0i % WSLOTS) * 1024);                \
            bf16x8 hb1 = *(const bf16x8*)(hp + (b1i % WSLOTS) * 1024);                \
            _Pragma("unroll") for (int e = 0; e < 8; ++e)                             \
                xf0[e] = (__bf16)((USEK) ? fmaf((CST) * dt, KP[e], y[e]) : y[e]);     \
            _Pragma("unroll") for (int e = 0; e < 8; ++e) {                           \
                const float va = (float)ha0[e];                                       \
                xf1[e] = (__bf16)fmaf(wa, (float)ha1[e] - va, va);                    \
            }                                                                         \
            _Pragma("unroll") for (int e = 0; e < 8; ++e) {                           \
                const float va = (float)hb0[e];                                       \
                xf2[e] = (__bf16)fmaf(wb, (float)hb1[e] - va, va);                    \
            }                                                                         \
        }                                                                             \
        /* ---- L0: x-frags already in regs ---- */                                   \
        {                                                                             \
            f32x4 a0 = bias0[0], a1 = bias0[1];                                       \
            a0 = MFMA(W0f[0][0], xf0, a0); a1 = MFMA(W0f[1][0], xf0, a1);             \
            a0 = MFMA(W0f[0][1], xf1, a0); a1 = MFMA(W0f[1][1], xf1, a1);             \
            a0 = MFMA(W0f[0][2], xf2, a0); a1 = MFMA(W0f[1][2], xf2, a1);             \
            bp4 p0, p1;                                                               \
            _Pragma("unroll") for (int j = 0; j < 4; ++j) {                           \
                p0.b[j] = (__bf16)fmaxf(a0[j], 0.0f);                                 \
                p1.b[j] = (__bf16)fmaxf(a1[j], 0.0f);                                 \
            }                                                                         \
            *(uint2*)(hA + m * 256 + ((wv * 64 + g * 8) ^ sw)) = p0.u;                \
            *(uint2*)(hA + m * 256 + ((wv * 64 + 32 + g * 8) ^ sw)) = p1.u;           \
        }                                                                             \
        wg_barrier();                                                                 \
        /* ---- L1 ---- */                                                            \
        {                                                                             \
            bf16x8 xh[4];                                                             \
            _Pragma("unroll") for (int kc = 0; kc < 4; ++kc)                          \
                xh[kc] = *(const bf16x8*)(hA + m * 256 + ((kc * 64 + g * 16) ^ sw));  \
            f32x4 a0 = bias1[0], a1 = bias1[1];                                       \
            _Pragma("unroll") for (int kc = 0; kc < 4; ++kc) {                        \
                a0 = MFMA(W1f[0][kc], xh[kc], a0);                                    \
                a1 = MFMA(W1f[1][kc], xh[kc], a1);                                    \
            }                                                                         \
            bp4 p0, p1;                                                               \
            _Pragma("unroll") for (int j = 0; j < 4; ++j) {                           \
                p0.b[j] = (__bf16)fmaxf(a0[j], 0.0f);                                 \
                p1.b[j] = (__bf16)fmaxf(a1[j], 0.0f);                                 \
            }                                                                         \
            *(uint2*)(hB + m * 256 + ((wv * 64 + g * 8) ^ sw)) = p0.u;                \
            *(uint2*)(hB + m * 256 + ((wv * 64 + 32 + g * 8) ^ sw)) = p1.u;           \
        }                                                                             \
        wg_barrier();                                                                 \
        /* ---- L2 + K-split L3 partial (h2 never crosses waves) ---- */              \
        {                                                                             \
            bf16x8 xh[4];                                                             \
            _Pragma("unroll") for (int kc = 0; kc < 4; ++kc)                          \
                xh[kc] = *(const bf16x8*)(hB + m * 256 + ((kc * 64 + g * 16) ^ sw));  \
            f32x4 a0 = bias2[0], a1 = bias2[1];                                       \
            _Pragma("unroll") for (int kc = 0; kc < 4; ++kc) {                        \
                a0 = MFMA(W2f[0][kc], xh[kc], a0);                                    \
                a1 = MFMA(W2f[1][kc], xh[kc], a1);                                    \
            }                                                                         \
            bp4 p0, p1;                                                               \
            _Pragma("unroll") for (int j = 0; j < 4; ++j) {                           \
                p0.b[j] = (__bf16)fmaxf(a0[j], 0.0f);                                 \
                p1.b[j] = (__bf16)fmaxf(a1[j], 0.0f);                                 \
            }                                                                         \
            /* same-wave regroup D-layout -> B-layout (lgkm only, no barrier) */      \
            *(uint2*)(h2w + m * 256 + ((g * 8) ^ sw)) = p0.u;                         \
            *(uint2*)(h2w + m * 256 + ((32 + g * 8) ^ sw)) = p1.u;                    \
            asm volatile("s_waitcnt lgkmcnt(0)" ::: "memory");                        \
            __builtin_amdgcn_sched_barrier(0);                                        \
            bf16x8 h2f = *(const bf16x8*)(h2w + m * 256 + ((g * 16) ^ sw));           \
            f32x4 ka = MFMA(W3f[0], h2f, kinit[0]);                                   \
            f32x4 kb = MFMA(W3f[1], h2f, kinit[1]);                                   \
            *(f32x4*)(kpw + m * 256 + ((g * 16) ^ sw)) = ka;                          \
            *(f32x4*)(kpw + m * 256 + ((64 + g * 16) ^ sw)) = kb;                     \
        }                                                                             \
        wg_barrier();                                                                 \
        /* ---- k-reduce: every wave sums 4 partials -> replicated k (B-layout) */    \
        _Pragma("unroll") for (int e = 0; e < 8; ++e) KD[e] = 0.0f;                   \
        _Pragma("unroll") for (int w4 = 0; w4 < 4; ++w4) {                            \
            const char* kr = kps[w4] + m * 256;                                       \
            f32x4 q0 = *(const f32x4*)(kr + ((g * 32) ^ sw));                         \
            f32x4 q1 = *(const f32x4*)(kr + ((g * 32 + 16) ^ sw));                    \
            _Pragma("unroll") for (int e = 0; e < 4; ++e) {                           \
                KD[e] += q0[e]; KD[e + 4] += q1[e];                                   \
            }                                                                         \
        }                                                                             \
    }

__global__ __launch_bounds__(256, 1) void dde_ks(
    const float* __restrict__ ts, const float* __restrict__ y0,
    const float* __restrict__ W0, const float* __restrict__ b0,
    const float* __restrict__ W1, const float* __restrict__ b1,
    const float* __restrict__ W2, const float* __restrict__ b2,
    const float* __restrict__ W3, const float* __restrict__ b3,
    float* __restrict__ out)
{
    __shared__ __align__(16) char hists[WSLOTS * 1024];  // [slot][g][m][8c] bf16, B-layout
    __shared__ __align__(16) char hA[16 * 256];
    __shared__ __align__(16) char hB[16 * 256];
    __shared__ __align__(16) char h2s[4][16 * 256];      // per-wave h2 regroup scratch
    __shared__ __align__(16) char kps[4][16 * 256];      // per-wave k-partials (f32)
    __shared__ float tsb[TT];
    // ~95 KB LDS

    const int tid  = threadIdx.x;
    const int lane = tid & 63;
    const int wv   = tid >> 6;        // wave 0..3 -> 32-col slice of hidden layers
    const int m    = lane & 15;       // batch row within block
    const int g    = lane >> 4;       // feature-octet index (B-layout)
    const int sw   = (m & 7) << 4;
    const int R0   = blockIdx.x * 16;
    char* h2w = h2s[wv];
    char* kpw = kps[wv];

    for (int idx = tid; idx < WSLOTS * 256; idx += 256) ((unsigned*)hists)[idx] = 0u;
    for (int idx = tid; idx < TT; idx += 256) tsb[idx] = ts[idx];

    // ---- register-resident weight fragments ----
    bf16x8 W0f[2][3], W1f[2][4], W2f[2][4], W3f[2];
    #pragma unroll
    for (int ti = 0; ti < 2; ++ti) {
        const int rw = wv * 32 + ti * 16 + m;
        #pragma unroll
        for (int kc = 0; kc < 3; ++kc) W0f[ti][kc] = ldw8(W0 + rw * 96 + kc * 32 + g * 8);
        #pragma unroll
        for (int kc = 0; kc < 4; ++kc) W1f[ti][kc] = ldw8(W1 + rw * 128 + kc * 32 + g * 8);
        #pragma unroll
        for (int kc = 0; kc < 4; ++kc) W2f[ti][kc] = ldw8(W2 + rw * 128 + kc * 32 + g * 8);
        // W3 K-slice: A[out o][k = wv*32 + g*8..+7]
        W3f[ti] = ldw8(W3 + (ti * 16 + m) * 128 + wv * 32 + g * 8);
    }
    f32x4 bias0[2], bias1[2], bias2[2], kinit[2];
    #pragma unroll
    for (int ti = 0; ti < 2; ++ti) {
        bias0[ti] = *(const f32x4*)(b0 + wv * 32 + ti * 16 + g * 4);
        bias1[ti] = *(const f32x4*)(b1 + wv * 32 + ti * 16 + g * 4);
        bias2[ti] = *(const f32x4*)(b2 + wv * 32 + ti * 16 + g * 4);
        if (wv == 0) kinit[ti] = *(const f32x4*)(b3 + ti * 16 + g * 4);
        else         kinit[ti] = f32x4{0.0f, 0.0f, 0.0f, 0.0f};   // bias added once
    }

    __syncthreads();   // hist zero complete

    // ---- state init (replicated, B-layout): y[e] = feature g*8+e of sample m ----
    float y[8], k1[8], k2[8], k3[8];
    {
        float4 v0 = *(const float4*)(y0 + (R0 + m) * DATA + g * 8);
        float4 v1 = *(const float4*)(y0 + (R0 + m) * DATA + g * 8 + 4);
        y[0] = v0.x; y[1] = v0.y; y[2] = v0.z; y[3] = v0.w;
        y[4] = v1.x; y[5] = v1.y; y[6] = v1.z; y[7] = v1.w;
        #pragma unroll
        for (int e = 0; e < 8; ++e) { k1[e] = 0.0f; k2[e] = 0.0f; k3[e] = 0.0f; }
        if (wv == 0) {
            bf16x8 hy;
            #pragma unroll
            for (int e = 0; e < 8; ++e) hy[e] = (__bf16)y[e];
            *(bf16x8*)(hists + g * 256 + m * 16) = hy;            // hist slot 0 = y0
            *(float4*)(out + (R0 + m) * DATA + g * 8) = v0;       // ys[0] = y0 exact
            *(float4*)(out + (R0 + m) * DATA + g * 8 + 4) = v1;
        }
    }
    if (blockIdx.x == 0 && tid == 0)
        out[(size_t)TT * BATCH * DATA] = 255.0f;   // tuple output 1: int32(T-1)
    __syncthreads();

    const float t0v  = tsb[0];
    const float ivd0 = 1.0f / (tsb[1] - tsb[0]);

    #pragma unroll 1
    for (int i = 0; i < TT - 1; ++i) {
        const float t  = tsb[i];
        const float dt = tsb[i + 1] - t;

        DO_STAGE(0, 0.0f,  k1, k1)
        DO_STAGE(1, 0.5f,  k1, k2)
        DO_STAGE(2, 0.75f, k2, k3)

        {   // RK combine (replicated); stores by wave 0 only (fire-and-forget)
            #pragma unroll
            for (int e = 0; e < 8; ++e) {
                const float ks = (2.0f / 9.0f) * k1[e] + (1.0f / 3.0f) * k2[e]
                               + (4.0f / 9.0f) * k3[e];
                y[e] = fmaf(dt, ks, y[e]);
            }
            if (wv == 0) {
                bf16x8 hy;
                #pragma unroll
                for (int e = 0; e < 8; ++e) hy[e] = (__bf16)y[e];
                *(bf16x8*)(hists + ((i + 1) % WSLOTS) * 1024 + g * 256 + m * 16) = hy;
                float4 o0, o1;
                o0.x = y[0]; o0.y = y[1]; o0.z = y[2]; o0.w = y[3];
                o1.x = y[4]; o1.y = y[5]; o1.z = y[6]; o1.w = y[7];
                float* op = out + (size_t)(i + 1) * BATCH * DATA + (R0 + m) * DATA + g * 8;
                *(float4*)op = o0;
                *(float4*)(op + 4) = o1;
            }
        }
        // hist slot i+1 first read at step >= i+26 (>=75 barriers later) -> safe;
        // hA reads(pre-b2) vs next writes(post-b3): 2 barriers apart; hB similar.
    }
}

extern "C" void kernel_launch(void* const* d_in, const int* in_sizes, int n_in,
                              void* d_out, int out_size, void* d_ws, size_t ws_size,
                              hipStream_t stream) {
    const float* ts = (const float*)d_in[0];
    const float* y0 = (const float*)d_in[1];
    const float* W0 = (const float*)d_in[2];
    const float* b0 = (const float*)d_in[3];
    const float* W1 = (const float*)d_in[4];
    const float* b1 = (const float*)d_in[5];
    const float* W2 = (const float*)d_in[6];
    const float* b2 = (const float*)d_in[7];
    const float* W3 = (const float*)d_in[8];
    const float* b3 = (const float*)d_in[9];

    dde_ks<<<dim3(BATCH / 16), dim3(256), 0, stream>>>(
        ts, y0, W0, b0, W1, b1, W2, b2, W3, b3, (float*)d_out);
}